// Round 4
// baseline (205.349 us; speedup 1.0000x reference)
//
#include <hip/hip_runtime.h>
#include <math.h>

#define BATCH 32
#define H 512
#define W 512
#define PAD 15
#define R 4                         /* output rows per wave */
#define BANDS (H / R)               /* 128 */
#define NWAVES (BATCH * BANDS)      /* 4096 */
#define WPB 4                       /* waves per block */
#define NBLOCKS (NWAVES / WPB)      /* 1024 */
#define INV_KK (1.0f / 961.0f)

/* Per-row fused weight+BCE using the segment-sum horizontal window.
   All locals constant-indexed -> SROA-safe. */
#define ROW_BODY(va, vb, yy)                                                  \
    {                                                                         \
        const float4* tp_ = (const float4*)(tb + (size_t)(yy) * W + x0);      \
        const float4* lp_ = (const float4*)(lb + (size_t)(yy) * W + x0);      \
        float4 t0_ = tp_[0], t1_ = tp_[1];                                    \
        float4 l0_ = lp_[0], l1_ = lp_[1];                                    \
        float p_[8];                                                          \
        p_[0] = (va).x;          p_[1] = p_[0] + (va).y;                      \
        p_[2] = p_[1] + (va).z;  p_[3] = p_[2] + (va).w;                      \
        p_[4] = p_[3] + (vb).x;  p_[5] = p_[4] + (vb).y;                      \
        p_[6] = p_[5] + (vb).z;  p_[7] = p_[6] + (vb).w;                      \
        const float tot_ = p_[7];                                             \
        float pm2_[8], pe_[7];                                                \
        _Pragma("unroll")                                                     \
        for (int k = 0; k < 8; ++k) pm2_[k] = __shfl_up(p_[k], 2);            \
        _Pragma("unroll")                                                     \
        for (int k = 0; k < 7; ++k) pe_[k] = __shfl_down(p_[k], 2);           \
        const float bm_ = __shfl_up(tot_, 1);                                 \
        const float dp_ = __shfl_down(tot_, 1);                               \
        const float base_ = (okm1 ? bm_ : 0.f) + tot_ + (okp1 ? dp_ : 0.f);   \
        float tv_[8] = {t0_.x, t0_.y, t0_.z, t0_.w, t1_.x, t1_.y, t1_.z, t1_.w}; \
        float lv_[8] = {l0_.x, l0_.y, l0_.z, l0_.w, l1_.x, l1_.y, l1_.z, l1_.w}; \
        _Pragma("unroll")                                                     \
        for (int k = 0; k < 8; ++k) {                                         \
            float aa_ = okm2 ? (pm2_[7] - pm2_[k]) : 0.f;                     \
            float ee_ = (k >= 1 && okp2) ? pe_[k - 1] : 0.f;                  \
            float hs_ = aa_ + base_ + ee_;                                    \
            float pooled_ = hs_ * INV_KK;                                     \
            float wgt_ = fmaf(5.f, fabsf(pooled_ - tv_[k]), 1.f);             \
            float al_ = fabsf(lv_[k]);                                        \
            float bce_ = fmaxf(lv_[k], 0.f) - lv_[k] * tv_[k]                 \
                         + __logf(1.f + __expf(-al_));                        \
            num = fmaf(wgt_, bce_, num);                                      \
            den += wgt_;                                                      \
        }                                                                     \
    }

__global__ __launch_bounds__(WPB * 64, 4)
void wbce_wave_kernel(const float* __restrict__ logits,
                      const float* __restrict__ targets,
                      float* __restrict__ partials) {
    __shared__ float rn[WPB], rd[WPB];

    const int tid  = threadIdx.x;
    const int lane = tid & 63;
    const int w    = tid >> 6;
    const int wid  = blockIdx.x * WPB + w;
    const int img  = wid >> 7;            /* wid / BANDS */
    const int band = wid & (BANDS - 1);
    const int y0   = band * R;
    const int x0   = lane * 8;

    const float* tb = targets + (size_t)img * H * W;
    const float* lb = logits  + (size_t)img * H * W;

    /* ---- Phase A: 4 vertical 31-row window sums, named accumulators ---- */
    float4 v0a = {0,0,0,0}, v0b = {0,0,0,0};
    float4 v1a = {0,0,0,0}, v1b = {0,0,0,0};
    float4 v2a = {0,0,0,0}, v2b = {0,0,0,0};
    float4 v3a = {0,0,0,0}, v3b = {0,0,0,0};

    /* row c covers dy = c-15; vs[j] needs dy in [j-15, j+15] <=> c in [j, j+30] */
    #pragma unroll
    for (int c = 0; c < 34; ++c) {
        const int y = y0 + c - PAD;
        float4 ra = {0,0,0,0}, rb = {0,0,0,0};
        if (y >= 0 && y < H) {
            const float4* p = (const float4*)(tb + (size_t)y * W + x0);
            ra = p[0]; rb = p[1];
        }
        if (c <= 30)           { v0a += ra; v0b += rb; }
        if (c >= 1 && c <= 31) { v1a += ra; v1b += rb; }
        if (c >= 2 && c <= 32) { v2a += ra; v2b += rb; }
        if (c >= 3)            { v3a += ra; v3b += rb; }
    }

    /* ---- Phase B: horizontal 31-sum + fused weight/BCE ---- */
    const bool okm2 = lane >= 2, okm1 = lane >= 1;
    const bool okp1 = lane <= 62, okp2 = lane <= 61;
    float num = 0.f, den = 0.f;

    ROW_BODY(v0a, v0b, y0 + 0)
    ROW_BODY(v1a, v1b, y0 + 1)
    ROW_BODY(v2a, v2b, y0 + 2)
    ROW_BODY(v3a, v3b, y0 + 3)

    /* ---- wave + block reduction, one partial pair per block ---- */
    #pragma unroll
    for (int off = 32; off > 0; off >>= 1) {
        num += __shfl_down(num, off);
        den += __shfl_down(den, off);
    }
    if (lane == 0) { rn[w] = num; rd[w] = den; }
    __syncthreads();
    if (tid == 0) {
        float n = 0.f, d = 0.f;
        #pragma unroll
        for (int i = 0; i < WPB; ++i) { n += rn[i]; d += rd[i]; }
        partials[blockIdx.x * 2]     = n;
        partials[blockIdx.x * 2 + 1] = d;
    }
}

/* 1024 partial pairs -> scalar. Image i owns pairs [i*32, i*32+32). */
__global__ __launch_bounds__(1024)
void wbce_finalize_kernel(const float* __restrict__ partials,
                          float* __restrict__ out) {
    __shared__ float rsum[16];
    const int t = threadIdx.x;
    float num = partials[t * 2];
    float den = partials[t * 2 + 1];
    #pragma unroll
    for (int off = 16; off > 0; off >>= 1) {
        num += __shfl_down(num, off, 32);
        den += __shfl_down(den, off, 32);
    }
    float ratio = 0.f;
    if ((t & 31) == 0) ratio = num / den;
    ratio += __shfl_down(ratio, 32);          /* lane0 += lane32 */
    const int lane = t & 63;
    const int wv = t >> 6;
    if (lane == 0) rsum[wv] = ratio;
    __syncthreads();
    if (t == 0) {
        float s = 0.f;
        #pragma unroll
        for (int i = 0; i < 16; ++i) s += rsum[i];
        out[0] = s / (float)BATCH;
    }
}

extern "C" void kernel_launch(void* const* d_in, const int* in_sizes, int n_in,
                              void* d_out, int out_size, void* d_ws, size_t ws_size,
                              hipStream_t stream) {
    const float* logits  = (const float*)d_in[0];
    const float* targets = (const float*)d_in[1];
    float* out = (float*)d_out;
    float* partials = (float*)d_ws;   /* NBLOCKS*2 floats = 8 KB */

    wbce_wave_kernel<<<NBLOCKS, WPB * 64, 0, stream>>>(logits, targets, partials);
    wbce_finalize_kernel<<<1, 1024, 0, stream>>>(partials, out);
}

// Round 5
// 41.228 us; speedup vs baseline: 4.9808x; 4.9808x over previous
//
#include <hip/hip_runtime.h>
#include <math.h>

#define BATCH 32
#define H 512
#define W 512
#define PAD 15
#define R 4                         /* output rows per wave */
#define BANDS (H / R)               /* 128 */
#define NWAVES (BATCH * BANDS)      /* 4096 */
#define WPB 4                       /* waves per block */
#define NBLOCKS (NWAVES / WPB)      /* 1024 */
#define INV_KK (1.0f / 961.0f)

/* Per-row fused weight+BCE using the segment-sum horizontal window.
   All locals constant-indexed -> SROA-safe. */
#define ROW_BODY(va, vb, yy)                                                  \
    {                                                                         \
        const float4* tp_ = (const float4*)(tb + (size_t)(yy) * W + x0);      \
        const float4* lp_ = (const float4*)(lb + (size_t)(yy) * W + x0);      \
        float4 t0_ = tp_[0], t1_ = tp_[1];                                    \
        float4 l0_ = lp_[0], l1_ = lp_[1];                                    \
        float p_[8];                                                          \
        p_[0] = (va).x;          p_[1] = p_[0] + (va).y;                      \
        p_[2] = p_[1] + (va).z;  p_[3] = p_[2] + (va).w;                      \
        p_[4] = p_[3] + (vb).x;  p_[5] = p_[4] + (vb).y;                      \
        p_[6] = p_[5] + (vb).z;  p_[7] = p_[6] + (vb).w;                      \
        const float tot_ = p_[7];                                             \
        float pm2_[8], pe_[7];                                                \
        _Pragma("unroll")                                                     \
        for (int k = 0; k < 8; ++k) pm2_[k] = __shfl_up(p_[k], 2);            \
        _Pragma("unroll")                                                     \
        for (int k = 0; k < 7; ++k) pe_[k] = __shfl_down(p_[k], 2);           \
        const float bm_ = __shfl_up(tot_, 1);                                 \
        const float dp_ = __shfl_down(tot_, 1);                               \
        const float base_ = (okm1 ? bm_ : 0.f) + tot_ + (okp1 ? dp_ : 0.f);   \
        float tv_[8] = {t0_.x, t0_.y, t0_.z, t0_.w, t1_.x, t1_.y, t1_.z, t1_.w}; \
        float lv_[8] = {l0_.x, l0_.y, l0_.z, l0_.w, l1_.x, l1_.y, l1_.z, l1_.w}; \
        _Pragma("unroll")                                                     \
        for (int k = 0; k < 8; ++k) {                                         \
            float aa_ = okm2 ? (pm2_[7] - pm2_[k]) : 0.f;                     \
            float ee_ = (k >= 1 && okp2) ? pe_[k - 1] : 0.f;                  \
            float hs_ = aa_ + base_ + ee_;                                    \
            float pooled_ = hs_ * INV_KK;                                     \
            float wgt_ = fmaf(5.f, fabsf(pooled_ - tv_[k]), 1.f);             \
            float al_ = fabsf(lv_[k]);                                        \
            float bce_ = fmaxf(lv_[k], 0.f) - lv_[k] * tv_[k]                 \
                         + __logf(1.f + __expf(-al_));                        \
            num = fmaf(wgt_, bce_, num);                                      \
            den += wgt_;                                                      \
        }                                                                     \
    }

__global__ __launch_bounds__(WPB * 64)
void wbce_wave_kernel(const float* __restrict__ logits,
                      const float* __restrict__ targets,
                      float* __restrict__ partials) {
    __shared__ float rn[WPB], rd[WPB];

    const int tid  = threadIdx.x;
    const int lane = tid & 63;
    const int w    = tid >> 6;
    const int wid  = blockIdx.x * WPB + w;
    const int img  = wid >> 7;            /* wid / BANDS */
    const int band = wid & (BANDS - 1);
    const int y0   = band * R;
    const int x0   = lane * 8;

    const float* tb = targets + (size_t)img * H * W;
    const float* lb = logits  + (size_t)img * H * W;

    /* ---- Phase A: 4 vertical 31-row window sums, named accumulators ---- */
    float4 v0a = {0,0,0,0}, v0b = {0,0,0,0};
    float4 v1a = {0,0,0,0}, v1b = {0,0,0,0};
    float4 v2a = {0,0,0,0}, v2b = {0,0,0,0};
    float4 v3a = {0,0,0,0}, v3b = {0,0,0,0};

    /* row c covers dy = c-15; vs[j] needs dy in [j-15, j+15] <=> c in [j, j+30] */
    #pragma unroll
    for (int c = 0; c < 34; ++c) {
        const int y = y0 + c - PAD;
        float4 ra = {0,0,0,0}, rb = {0,0,0,0};
        if (y >= 0 && y < H) {
            const float4* p = (const float4*)(tb + (size_t)y * W + x0);
            ra = p[0]; rb = p[1];
        }
        if (c <= 30)           { v0a += ra; v0b += rb; }
        if (c >= 1 && c <= 31) { v1a += ra; v1b += rb; }
        if (c >= 2 && c <= 32) { v2a += ra; v2b += rb; }
        if (c >= 3)            { v3a += ra; v3b += rb; }
    }

    /* ---- Phase B: horizontal 31-sum + fused weight/BCE ---- */
    const bool okm2 = lane >= 2, okm1 = lane >= 1;
    const bool okp1 = lane <= 62, okp2 = lane <= 61;
    float num = 0.f, den = 0.f;

    ROW_BODY(v0a, v0b, y0 + 0)
    ROW_BODY(v1a, v1b, y0 + 1)
    ROW_BODY(v2a, v2b, y0 + 2)
    ROW_BODY(v3a, v3b, y0 + 3)

    /* ---- wave + block reduction, one partial pair per block ---- */
    #pragma unroll
    for (int off = 32; off > 0; off >>= 1) {
        num += __shfl_down(num, off);
        den += __shfl_down(den, off);
    }
    if (lane == 0) { rn[w] = num; rd[w] = den; }
    __syncthreads();
    if (tid == 0) {
        float n = 0.f, d = 0.f;
        #pragma unroll
        for (int i = 0; i < WPB; ++i) { n += rn[i]; d += rd[i]; }
        partials[blockIdx.x * 2]     = n;
        partials[blockIdx.x * 2 + 1] = d;
    }
}

/* 1024 partial pairs -> scalar. Image i owns pairs [i*32, i*32+32). */
__global__ __launch_bounds__(1024)
void wbce_finalize_kernel(const float* __restrict__ partials,
                          float* __restrict__ out) {
    __shared__ float rsum[16];
    const int t = threadIdx.x;
    float num = partials[t * 2];
    float den = partials[t * 2 + 1];
    #pragma unroll
    for (int off = 16; off > 0; off >>= 1) {
        num += __shfl_down(num, off, 32);
        den += __shfl_down(den, off, 32);
    }
    float ratio = 0.f;
    if ((t & 31) == 0) ratio = num / den;
    ratio += __shfl_down(ratio, 32);          /* lane0 += lane32 */
    const int lane = t & 63;
    const int wv = t >> 6;
    if (lane == 0) rsum[wv] = ratio;
    __syncthreads();
    if (t == 0) {
        float s = 0.f;
        #pragma unroll
        for (int i = 0; i < 16; ++i) s += rsum[i];
        out[0] = s / (float)BATCH;
    }
}

extern "C" void kernel_launch(void* const* d_in, const int* in_sizes, int n_in,
                              void* d_out, int out_size, void* d_ws, size_t ws_size,
                              hipStream_t stream) {
    const float* logits  = (const float*)d_in[0];
    const float* targets = (const float*)d_in[1];
    float* out = (float*)d_out;
    float* partials = (float*)d_ws;   /* NBLOCKS*2 floats = 8 KB */

    wbce_wave_kernel<<<NBLOCKS, WPB * 64, 0, stream>>>(logits, targets, partials);
    wbce_finalize_kernel<<<1, 1024, 0, stream>>>(partials, out);
}

// Round 6
// 37.624 us; speedup vs baseline: 5.4580x; 1.0958x over previous
//
#include <hip/hip_runtime.h>
#include <math.h>

#define BATCH 32
#define H 512
#define W 512
#define PAD 15
#define R 4                         /* output rows per wave */
#define BANDS (H / R)               /* 128 */
#define NWAVES (BATCH * BANDS)      /* 4096 */
#define WPB 4                       /* waves per block */
#define NBLOCKS (NWAVES / WPB)      /* 1024 */
#define INV_KK (1.0f / 961.0f)

/* Per-row fused weight+BCE using the segment-sum horizontal window.
   All locals constant-indexed -> SROA-safe. (verified R2/R4/R5) */
#define ROW_BODY(va, vb, yy)                                                  \
    {                                                                         \
        const float4* tp_ = (const float4*)(tb + (size_t)(yy) * W + x0);      \
        const float4* lp_ = (const float4*)(lb + (size_t)(yy) * W + x0);      \
        float4 t0_ = tp_[0], t1_ = tp_[1];                                    \
        float4 l0_ = lp_[0], l1_ = lp_[1];                                    \
        float p_[8];                                                          \
        p_[0] = (va).x;          p_[1] = p_[0] + (va).y;                      \
        p_[2] = p_[1] + (va).z;  p_[3] = p_[2] + (va).w;                      \
        p_[4] = p_[3] + (vb).x;  p_[5] = p_[4] + (vb).y;                      \
        p_[6] = p_[5] + (vb).z;  p_[7] = p_[6] + (vb).w;                      \
        const float tot_ = p_[7];                                             \
        float pm2_[8], pe_[7];                                                \
        _Pragma("unroll")                                                     \
        for (int k = 0; k < 8; ++k) pm2_[k] = __shfl_up(p_[k], 2);            \
        _Pragma("unroll")                                                     \
        for (int k = 0; k < 7; ++k) pe_[k] = __shfl_down(p_[k], 2);           \
        const float bm_ = __shfl_up(tot_, 1);                                 \
        const float dp_ = __shfl_down(tot_, 1);                               \
        const float base_ = (okm1 ? bm_ : 0.f) + tot_ + (okp1 ? dp_ : 0.f);   \
        float tv_[8] = {t0_.x, t0_.y, t0_.z, t0_.w, t1_.x, t1_.y, t1_.z, t1_.w}; \
        float lv_[8] = {l0_.x, l0_.y, l0_.z, l0_.w, l1_.x, l1_.y, l1_.z, l1_.w}; \
        _Pragma("unroll")                                                     \
        for (int k = 0; k < 8; ++k) {                                         \
            float aa_ = okm2 ? (pm2_[7] - pm2_[k]) : 0.f;                     \
            float ee_ = (k >= 1 && okp2) ? pe_[k - 1] : 0.f;                  \
            float hs_ = aa_ + base_ + ee_;                                    \
            float pooled_ = hs_ * INV_KK;                                     \
            float wgt_ = fmaf(5.f, fabsf(pooled_ - tv_[k]), 1.f);             \
            float al_ = fabsf(lv_[k]);                                        \
            float bce_ = fmaxf(lv_[k], 0.f) - lv_[k] * tv_[k]                 \
                         + __logf(1.f + __expf(-al_));                        \
            num = fmaf(wgt_, bce_, num);                                      \
            den += wgt_;                                                      \
        }                                                                     \
    }

/* row c covers image row y = y0 + c - 15, c = 0..33.
   S = sum of all 34 rows; pre/suf partial row-sums let us derive:
     v0 = S - (r31+r32+r33)         = S - s3
     v1 = S - r0 - (r32+r33)        = S - pA - s2
     v2 = S - (r0+r1) - r33         = S - pB - s1
     v3 = S - (r0+r1+r2)            = S - pC            */
#define LOAD_FAST(ra, rb, y)                                                  \
    { const float4* p_ = (const float4*)(tb + (size_t)(y) * W + x0);          \
      ra = p_[0]; rb = p_[1]; }

#define LOAD_SAFE(ra, rb, y)                                                  \
    { ra = make_float4(0.f, 0.f, 0.f, 0.f); rb = ra;                          \
      if ((unsigned)(y) < (unsigned)H) {                                      \
          const float4* p_ = (const float4*)(tb + (size_t)(y) * W + x0);      \
          ra = p_[0]; rb = p_[1]; } }

#define CHUNK(LOADER, C0, C1)                                                 \
    _Pragma("unroll")                                                         \
    for (int c = (C0); c < (C1); ++c) {                                       \
        const int y = y0 + c - PAD;                                           \
        float4 ra, rb;                                                        \
        LOADER(ra, rb, y)                                                     \
        Sa += ra; Sb += rb;                                                   \
        if (c == 0)  { pAa = ra; pAb = rb; }                                  \
        if (c == 1)  { pBa = pAa + ra; pBb = pAb + rb; }                      \
        if (c == 2)  { pCa = pBa + ra; pCb = pBb + rb; }                      \
        if (c == 31) { s3a = ra; s3b = rb; }                                  \
        if (c == 32) { s3a += ra; s3b += rb; s2a = ra; s2b = rb; }            \
        if (c == 33) { s3a += ra; s3b += rb; s2a += ra; s2b += rb;            \
                       s1a = ra; s1b = rb; }                                  \
    }

#define STREAM(LOADER)                                                        \
    CHUNK(LOADER, 0, 6)   __builtin_amdgcn_sched_barrier(0);                  \
    CHUNK(LOADER, 6, 12)  __builtin_amdgcn_sched_barrier(0);                  \
    CHUNK(LOADER, 12, 18) __builtin_amdgcn_sched_barrier(0);                  \
    CHUNK(LOADER, 18, 24) __builtin_amdgcn_sched_barrier(0);                  \
    CHUNK(LOADER, 24, 30) __builtin_amdgcn_sched_barrier(0);                  \
    CHUNK(LOADER, 30, 34)

__global__ __launch_bounds__(WPB * 64)
void wbce_wave_kernel(const float* __restrict__ logits,
                      const float* __restrict__ targets,
                      float* __restrict__ partials) {
    __shared__ float rn[WPB], rd[WPB];

    const int tid  = threadIdx.x;
    const int lane = tid & 63;
    const int w    = tid >> 6;
    const int wid  = blockIdx.x * WPB + w;
    const int img  = wid >> 7;            /* wid / BANDS */
    const int band = wid & (BANDS - 1);
    const int y0   = band * R;
    const int x0   = lane * 8;

    const float* tb = targets + (size_t)img * H * W;
    const float* lb = logits  + (size_t)img * H * W;

    /* ---- Phase A: stream 34 rows, keep S + 3 prefixes + 3 suffixes ---- */
    float4 Sa = {0,0,0,0}, Sb = {0,0,0,0};
    float4 pAa, pAb, pBa, pBb, pCa, pCb;
    float4 s1a, s1b, s2a, s2b, s3a, s3b;

    if (y0 >= PAD && y0 + 18 < H) {       /* interior band: no bounds checks */
        STREAM(LOAD_FAST)
    } else {
        STREAM(LOAD_SAFE)
    }

    /* ---- Phase B: derive each vertical window JIT + fused weight/BCE ---- */
    const bool okm2 = lane >= 2, okm1 = lane >= 1;
    const bool okp1 = lane <= 62, okp2 = lane <= 61;
    float num = 0.f, den = 0.f;

    {
        float4 va = Sa - s3a, vb = Sb - s3b;
        ROW_BODY(va, vb, y0 + 0)
    }
    {
        float4 va = (Sa - pAa) - s2a, vb = (Sb - pAb) - s2b;
        ROW_BODY(va, vb, y0 + 1)
    }
    {
        float4 va = (Sa - pBa) - s1a, vb = (Sb - pBb) - s1b;
        ROW_BODY(va, vb, y0 + 2)
    }
    {
        float4 va = Sa - pCa, vb = Sb - pCb;
        ROW_BODY(va, vb, y0 + 3)
    }

    /* ---- wave + block reduction, one partial pair per block ---- */
    #pragma unroll
    for (int off = 32; off > 0; off >>= 1) {
        num += __shfl_down(num, off);
        den += __shfl_down(den, off);
    }
    if (lane == 0) { rn[w] = num; rd[w] = den; }
    __syncthreads();
    if (tid == 0) {
        float n = 0.f, d = 0.f;
        #pragma unroll
        for (int i = 0; i < WPB; ++i) { n += rn[i]; d += rd[i]; }
        partials[blockIdx.x * 2]     = n;
        partials[blockIdx.x * 2 + 1] = d;
    }
}

/* 1024 partial pairs -> scalar. Image i owns pairs [i*32, i*32+32). */
__global__ __launch_bounds__(1024)
void wbce_finalize_kernel(const float* __restrict__ partials,
                          float* __restrict__ out) {
    __shared__ float rsum[16];
    const int t = threadIdx.x;
    float num = partials[t * 2];
    float den = partials[t * 2 + 1];
    #pragma unroll
    for (int off = 16; off > 0; off >>= 1) {
        num += __shfl_down(num, off, 32);
        den += __shfl_down(den, off, 32);
    }
    float ratio = 0.f;
    if ((t & 31) == 0) ratio = num / den;
    ratio += __shfl_down(ratio, 32);          /* lane0 += lane32 */
    const int lane = t & 63;
    const int wv = t >> 6;
    if (lane == 0) rsum[wv] = ratio;
    __syncthreads();
    if (t == 0) {
        float s = 0.f;
        #pragma unroll
        for (int i = 0; i < 16; ++i) s += rsum[i];
        out[0] = s / (float)BATCH;
    }
}

extern "C" void kernel_launch(void* const* d_in, const int* in_sizes, int n_in,
                              void* d_out, int out_size, void* d_ws, size_t ws_size,
                              hipStream_t stream) {
    const float* logits  = (const float*)d_in[0];
    const float* targets = (const float*)d_in[1];
    float* out = (float*)d_out;
    float* partials = (float*)d_ws;   /* NBLOCKS*2 floats = 8 KB */

    wbce_wave_kernel<<<NBLOCKS, WPB * 64, 0, stream>>>(logits, targets, partials);
    wbce_finalize_kernel<<<1, 1024, 0, stream>>>(partials, out);
}

// Round 7
// 34.814 us; speedup vs baseline: 5.8985x; 1.0807x over previous
//
#include <hip/hip_runtime.h>
#include <math.h>

#define BATCH 32
#define H 512
#define W 512
#define PAD 15
#define R 4                         /* output rows per wave */
#define BANDS (H / R)               /* 128 */
#define NWAVES (BATCH * BANDS)      /* 4096 */
#define WPB 4                       /* waves per block */
#define NBLOCKS (NWAVES / WPB)      /* 1024 */
#define NXCD 8
#define INV_KK (1.0f / 961.0f)

/* Per-row fused weight+BCE using the segment-sum horizontal window.
   All locals constant-indexed -> SROA-safe. (verified R2..R6, absmax 0) */
#define ROW_BODY(va, vb, yy)                                                  \
    {                                                                         \
        const float4* tp_ = (const float4*)(tb + (size_t)(yy) * W + x0);      \
        const float4* lp_ = (const float4*)(lb + (size_t)(yy) * W + x0);      \
        float4 t0_ = tp_[0], t1_ = tp_[1];                                    \
        float4 l0_ = lp_[0], l1_ = lp_[1];                                    \
        float p_[8];                                                          \
        p_[0] = (va).x;          p_[1] = p_[0] + (va).y;                      \
        p_[2] = p_[1] + (va).z;  p_[3] = p_[2] + (va).w;                      \
        p_[4] = p_[3] + (vb).x;  p_[5] = p_[4] + (vb).y;                      \
        p_[6] = p_[5] + (vb).z;  p_[7] = p_[6] + (vb).w;                      \
        const float tot_ = p_[7];                                             \
        float pm2_[8], pe_[7];                                                \
        _Pragma("unroll")                                                     \
        for (int k = 0; k < 8; ++k) pm2_[k] = __shfl_up(p_[k], 2);            \
        _Pragma("unroll")                                                     \
        for (int k = 0; k < 7; ++k) pe_[k] = __shfl_down(p_[k], 2);           \
        const float bm_ = __shfl_up(tot_, 1);                                 \
        const float dp_ = __shfl_down(tot_, 1);                               \
        const float base_ = (okm1 ? bm_ : 0.f) + tot_ + (okp1 ? dp_ : 0.f);   \
        float tv_[8] = {t0_.x, t0_.y, t0_.z, t0_.w, t1_.x, t1_.y, t1_.z, t1_.w}; \
        float lv_[8] = {l0_.x, l0_.y, l0_.z, l0_.w, l1_.x, l1_.y, l1_.z, l1_.w}; \
        _Pragma("unroll")                                                     \
        for (int k = 0; k < 8; ++k) {                                         \
            float aa_ = okm2 ? (pm2_[7] - pm2_[k]) : 0.f;                     \
            float ee_ = (k >= 1 && okp2) ? pe_[k - 1] : 0.f;                  \
            float hs_ = aa_ + base_ + ee_;                                    \
            float pooled_ = hs_ * INV_KK;                                     \
            float wgt_ = fmaf(5.f, fabsf(pooled_ - tv_[k]), 1.f);             \
            float al_ = fabsf(lv_[k]);                                        \
            float bce_ = fmaxf(lv_[k], 0.f) - lv_[k] * tv_[k]                 \
                         + __logf(1.f + __expf(-al_));                        \
            num = fmaf(wgt_, bce_, num);                                      \
            den += wgt_;                                                      \
        }                                                                     \
    }

#define LOAD_FAST(ra, rb, y)                                                  \
    { const float4* p_ = (const float4*)(tb + (size_t)(y) * W + x0);          \
      ra = p_[0]; rb = p_[1]; }

#define LOAD_SAFE(ra, rb, y)                                                  \
    { ra = make_float4(0.f, 0.f, 0.f, 0.f); rb = ra;                          \
      if ((unsigned)(y) < (unsigned)H) {                                      \
          const float4* p_ = (const float4*)(tb + (size_t)(y) * W + x0);      \
          ra = p_[0]; rb = p_[1]; } }

/* sum rows y0-15 .. y0+15 into (va_, vb_); chunked so <=7 rows in flight */
#define CHUNKV(LOADER, C0, C1)                                                \
    _Pragma("unroll")                                                         \
    for (int c = (C0); c < (C1); ++c) {                                       \
        const int y = y0 + c - PAD;                                           \
        float4 ra, rb;                                                        \
        LOADER(ra, rb, y)                                                     \
        va_ += ra; vb_ += rb;                                                 \
    }

#define STREAM31(LOADER)                                                      \
    CHUNKV(LOADER, 0, 6)   __builtin_amdgcn_sched_barrier(0);                 \
    CHUNKV(LOADER, 6, 12)  __builtin_amdgcn_sched_barrier(0);                 \
    CHUNKV(LOADER, 12, 18) __builtin_amdgcn_sched_barrier(0);                 \
    CHUNKV(LOADER, 18, 24) __builtin_amdgcn_sched_barrier(0);                 \
    CHUNKV(LOADER, 24, 31)

/* slide + ROW_BODY sequence; prefetch enter/leave rows before the math that
   hides their latency */
#define PHASE_B(LOADER)                                                       \
    {                                                                         \
        float4 e0a, e0b, l0a, l0b;                                            \
        LOADER(e0a, e0b, y0 + 16) LOADER(l0a, l0b, y0 - 15)                   \
        ROW_BODY(va_, vb_, y0 + 0)                                            \
        va_ += e0a - l0a; vb_ += e0b - l0b;                                   \
        float4 e1a, e1b, l1a, l1b;                                            \
        LOADER(e1a, e1b, y0 + 17) LOADER(l1a, l1b, y0 - 14)                   \
        ROW_BODY(va_, vb_, y0 + 1)                                            \
        va_ += e1a - l1a; vb_ += e1b - l1b;                                   \
        float4 e2a, e2b, l2a, l2b;                                            \
        LOADER(e2a, e2b, y0 + 18) LOADER(l2a, l2b, y0 - 13)                   \
        ROW_BODY(va_, vb_, y0 + 2)                                            \
        va_ += e2a - l2a; vb_ += e2b - l2b;                                   \
        ROW_BODY(va_, vb_, y0 + 3)                                            \
    }

__global__ __launch_bounds__(WPB * 64)
void wbce_wave_kernel(const float* __restrict__ logits,
                      const float* __restrict__ targets,
                      float* __restrict__ partials) {
    __shared__ float rn[WPB], rd[WPB];

    const int tid  = threadIdx.x;
    const int lane = tid & 63;
    const int w    = tid >> 6;

    /* XCD-aware bijective swizzle: 128 consecutive blocks (4 images) per XCD
       so vertically-adjacent blocks (30 shared halo rows) share an L2 */
    const int bid  = (int)blockIdx.x;
    const int sbid = (bid & (NXCD - 1)) * (NBLOCKS / NXCD) + (bid >> 3);

    const int wid  = sbid * WPB + w;
    const int img  = wid >> 7;            /* wid / BANDS */
    const int band = wid & (BANDS - 1);
    const int y0   = band * R;
    const int x0   = lane * 8;

    const float* tb = targets + (size_t)img * H * W;
    const float* lb = logits  + (size_t)img * H * W;

    const bool okm2 = lane >= 2, okm1 = lane >= 1;
    const bool okp1 = lane <= 62, okp2 = lane <= 61;
    float num = 0.f, den = 0.f;

    float4 va_ = {0, 0, 0, 0}, vb_ = {0, 0, 0, 0};

    if (y0 >= PAD && y0 + 19 <= H) {      /* interior band: no bounds checks */
        STREAM31(LOAD_FAST)
        PHASE_B(LOAD_FAST)
    } else {
        STREAM31(LOAD_SAFE)
        PHASE_B(LOAD_SAFE)
    }

    /* ---- wave + block reduction, one partial pair per block ---- */
    #pragma unroll
    for (int off = 32; off > 0; off >>= 1) {
        num += __shfl_down(num, off);
        den += __shfl_down(den, off);
    }
    if (lane == 0) { rn[w] = num; rd[w] = den; }
    __syncthreads();
    if (tid == 0) {
        float n = 0.f, d = 0.f;
        #pragma unroll
        for (int i = 0; i < WPB; ++i) { n += rn[i]; d += rd[i]; }
        partials[sbid * 2]     = n;
        partials[sbid * 2 + 1] = d;
    }
}

/* 1024 partial pairs -> scalar. Image i owns pairs [i*32, i*32+32). */
__global__ __launch_bounds__(1024)
void wbce_finalize_kernel(const float* __restrict__ partials,
                          float* __restrict__ out) {
    __shared__ float rsum[16];
    const int t = threadIdx.x;
    float num = partials[t * 2];
    float den = partials[t * 2 + 1];
    #pragma unroll
    for (int off = 16; off > 0; off >>= 1) {
        num += __shfl_down(num, off, 32);
        den += __shfl_down(den, off, 32);
    }
    float ratio = 0.f;
    if ((t & 31) == 0) ratio = num / den;
    ratio += __shfl_down(ratio, 32);          /* lane0 += lane32 */
    const int lane = t & 63;
    const int wv = t >> 6;
    if (lane == 0) rsum[wv] = ratio;
    __syncthreads();
    if (t == 0) {
        float s = 0.f;
        #pragma unroll
        for (int i = 0; i < 16; ++i) s += rsum[i];
        out[0] = s / (float)BATCH;
    }
}

extern "C" void kernel_launch(void* const* d_in, const int* in_sizes, int n_in,
                              void* d_out, int out_size, void* d_ws, size_t ws_size,
                              hipStream_t stream) {
    const float* logits  = (const float*)d_in[0];
    const float* targets = (const float*)d_in[1];
    float* out = (float*)d_out;
    float* partials = (float*)d_ws;   /* NBLOCKS*2 floats = 8 KB */

    wbce_wave_kernel<<<NBLOCKS, WPB * 64, 0, stream>>>(logits, targets, partials);
    wbce_finalize_kernel<<<1, 1024, 0, stream>>>(partials, out);
}